// Round 6
// baseline (17266.344 us; speedup 1.0000x reference)
//
#include <hip/hip_runtime.h>
#include <hip/hip_fp16.h>
#include <cmath>

#define B_ 32
#define S_ 128
#define T_ 64
#define STEPS_ 63
#define V_ 32000
#define E_ 512
#define H_ 512

typedef __attribute__((ext_vector_type(4))) float f32x4;
typedef __attribute__((ext_vector_type(8))) short bf16x8;

__device__ inline short f2bf(float x) {
  unsigned u = __builtin_bit_cast(unsigned, x);
  u = (u + 0x7fffu + ((u >> 16) & 1u)) >> 16;
  return (short)u;
}
__device__ inline float bf2f(short h) {
  unsigned u = ((unsigned)(unsigned short)h) << 16;
  return __builtin_bit_cast(float, u);
}

// ---------------- pack GRU weight trio -> f16 {RZ half2, N half}, layout [k][u] ----
// W is [1536][ldw]; gate rows: r=u, z=512+u, n=1024+u; k-column = col0+k.
__global__ __launch_bounds__(256) void k_pack_rzn(
    const float* __restrict__ W, int ldw, int col0,
    __half2* __restrict__ RZ, __half* __restrict__ N) {
  int idx = blockIdx.x * 256 + threadIdx.x;  // 512*512, idx = k*512+u
  int k = idx >> 9, u = idx & 511;
  float wr = W[(long)u * ldw + col0 + k];
  float wz = W[(long)(512 + u) * ldw + col0 + k];
  float wn = W[(long)(1024 + u) * ldw + col0 + k];
  RZ[idx] = __halves2half2(__float2half(wr), __float2half(wz));
  N[idx] = __float2half(wn);
}

// ---------------- pack Wc [512][1024] -> half2 pairs: P[kk*512+i] = {Wc[i][2kk], Wc[i][2kk+1]} ----
__global__ __launch_bounds__(256) void k_pack_wc(
    const float* __restrict__ Wc, __half2* __restrict__ P) {
  int idx = blockIdx.x * 256 + threadIdx.x;  // 512*512, idx = kk*512+i
  int kk = idx >> 9, i = idx & 511;
  float a = Wc[(long)i * 1024 + 2 * kk];
  float b = Wc[(long)i * 1024 + 2 * kk + 1];
  P[idx] = __halves2half2(__float2half(a), __float2half(b));
}

// ---------------- MFMA bf16 split-precision GEMM (R1/R2-proven) ----------------
__global__ __launch_bounds__(256) void k_mfma_gemm(
    const float* __restrict__ A, const float* __restrict__ emb,
    const int* __restrict__ tok, int amode,
    const float* __restrict__ Bmat, long ldb,
    const float* __restrict__ bias,
    float* __restrict__ out, long sb, long st,
    int M, int N, int K) {
  __shared__ short Ah[128 * 40];
  __shared__ short Al[128 * 40];
  __shared__ short Bh[128 * 40];
  __shared__ short Bl[128 * 40];
  int t = threadIdx.x;
  int n0 = blockIdx.x * 128, m0 = blockIdx.y * 128;
  int ar = t >> 2, ac = (t & 3) * 8;

  const float* arow0;
  const float* arow1;
  {
    int m = m0 + ar;       int mc = m < M ? m : M - 1;
    int m2 = m0 + ar + 64; int mc2 = m2 < M ? m2 : M - 1;
    if (amode == 0) {
      arow0 = A + (long)mc * K;
      arow1 = A + (long)mc2 * K;
    } else {
      int b = mc & 31, q = mc >> 5;
      int tk = (amode == 1) ? tok[b * S_ + q] : tok[b * T_ + q];
      arow0 = emb + (long)tk * K;
      b = mc2 & 31; q = mc2 >> 5;
      tk = (amode == 1) ? tok[b * S_ + q] : tok[b * T_ + q];
      arow1 = emb + (long)tk * K;
    }
  }
  const float* brow0 = Bmat + (long)(n0 + ar) * ldb;
  const float* brow1 = Bmat + (long)(n0 + ar + 64) * ldb;

  int lane = t & 63, wave = t >> 6;
  int wm = (wave >> 1) * 64, wn = (wave & 1) * 64;
  int lr = lane & 15, lk = lane >> 4;
  f32x4 acc[4][4] = {};

  for (int k0 = 0; k0 < K; k0 += 32) {
    auto stage = [&](const float* rowp, short* Dh, short* Dl, int r) {
      float4 x0 = *(const float4*)(rowp + k0 + ac);
      float4 x1 = *(const float4*)(rowp + k0 + ac + 4);
      float xs[8] = {x0.x, x0.y, x0.z, x0.w, x1.x, x1.y, x1.z, x1.w};
      bf16x8 hi, lo;
#pragma unroll
      for (int i = 0; i < 8; ++i) {
        short h = f2bf(xs[i]);
        hi[i] = h;
        lo[i] = f2bf(xs[i] - bf2f(h));
      }
      *(bf16x8*)&Dh[r * 40 + ac] = hi;
      *(bf16x8*)&Dl[r * 40 + ac] = lo;
    };
    stage(arow0, Ah, Al, ar);
    stage(arow1, Ah, Al, ar + 64);
    stage(brow0, Bh, Bl, ar);
    stage(brow1, Bh, Bl, ar + 64);
    __syncthreads();

    bf16x8 a_h[4], a_l[4], b_h[4], b_l[4];
#pragma unroll
    for (int i = 0; i < 4; ++i) {
      int ra = (wm + i * 16 + lr) * 40 + lk * 8;
      a_h[i] = *(const bf16x8*)&Ah[ra];
      a_l[i] = *(const bf16x8*)&Al[ra];
      int rb = (wn + i * 16 + lr) * 40 + lk * 8;
      b_h[i] = *(const bf16x8*)&Bh[rb];
      b_l[i] = *(const bf16x8*)&Bl[rb];
    }
#pragma unroll
    for (int i = 0; i < 4; ++i)
#pragma unroll
      for (int j = 0; j < 4; ++j) {
        acc[i][j] = __builtin_amdgcn_mfma_f32_16x16x32_bf16(a_l[i], b_h[j], acc[i][j], 0, 0, 0);
        acc[i][j] = __builtin_amdgcn_mfma_f32_16x16x32_bf16(a_h[i], b_l[j], acc[i][j], 0, 0, 0);
        acc[i][j] = __builtin_amdgcn_mfma_f32_16x16x32_bf16(a_h[i], b_h[j], acc[i][j], 0, 0, 0);
      }
    __syncthreads();
  }

#pragma unroll
  for (int i = 0; i < 4; ++i) {
#pragma unroll
    for (int r = 0; r < 4; ++r) {
      int m = m0 + wm + i * 16 + lk * 4 + r;
      if (m >= M) continue;
      long base = (long)(m & 31) * sb + (long)(m >> 5) * st;
#pragma unroll
      for (int j = 0; j < 4; ++j) {
        int n = n0 + wn + j * 16 + lr;
        out[base + n] = acc[i][j][r] + bias[n];
      }
    }
  }
}

// ---------------- encoder: 32 blocks x 1024 threads, f16 weights, k-split halves ----
__global__ __launch_bounds__(1024) void k_enc_all(
    const float* __restrict__ gi_all,     // [S*B][1536], row = s*32+b (bih folded)
    const __half2* __restrict__ RZ, const __half* __restrict__ N,
    const float* __restrict__ bhh, const int* __restrict__ lens,
    float* __restrict__ h_out, float* __restrict__ EO) {
  __shared__ __align__(16) float hs[512];
  __shared__ float pG[2][3][512];
  int b = blockIdx.x, t = threadIdx.x;
  int u = t & 511, hf = t >> 9;
  int len = lens[b];
  float bhr = 0, bhz = 0, bhn = 0;
  if (t < 512) { bhr = bhh[u]; bhz = bhh[512 + u]; bhn = bhh[1024 + u]; hs[u] = 0.f; }
  __syncthreads();
  int k0 = hf * 256;

  for (int s = 0; s < S_; ++s) {
    float ar = 0.f, az = 0.f, an = 0.f;
#pragma unroll 8
    for (int k = k0; k < k0 + 256; ++k) {
      float hk = hs[k];
      float2 rz = __half22float2(RZ[k * 512 + u]);
      float wn = __half2float(N[k * 512 + u]);
      ar += hk * rz.x; az += hk * rz.y; an += hk * wn;
    }
    pG[hf][0][u] = ar; pG[hf][1][u] = az; pG[hf][2][u] = an;
    __syncthreads();
    if (t < 512) {
      const float* gi = gi_all + ((long)s * 32 + b) * 1536;
      float AR = pG[0][0][u] + pG[1][0][u] + bhr;
      float AZ = pG[0][1][u] + pG[1][1][u] + bhz;
      float AN = pG[0][2][u] + pG[1][2][u] + bhn;
      float r = 1.f / (1.f + expf(-(gi[u] + AR)));
      float z = 1.f / (1.f + expf(-(gi[512 + u] + AZ)));
      float n = tanhf(gi[1024 + u] + r * AN);
      float hold = hs[u];
      float hn = (1.f - z) * n + z * hold;
      bool valid = s < len;
      EO[((long)b * 128 + s) * 512 + u] = valid ? hn : 0.f;
      hs[u] = valid ? hn : hold;
    }
    __syncthreads();
  }
  if (t < 512) h_out[b * 512 + u] = hs[u];
}

// ---------------- decoder: 32 blocks x 1024 threads, f16 weights ----------------
__global__ __launch_bounds__(1024) void k_dec_all(
    const float* __restrict__ gie,        // [STEPS*B][1536], row = t*32+b
    const float* __restrict__ EO,         // [32][128][512]
    const __half2* __restrict__ RZh, const __half* __restrict__ Nh,  // Whh_d
    const __half2* __restrict__ RZc, const __half* __restrict__ Nc,  // Wih_d ctx part
    const __half2* __restrict__ WcP,
    const float* __restrict__ bhh, const float* __restrict__ bc,
    const int* __restrict__ lens, const float* __restrict__ h_init,
    float* __restrict__ ccall, float* __restrict__ attns) {
  __shared__ __align__(16) float hs[512];
  __shared__ __align__(16) float cs[512];
  __shared__ float sc[128];
  __shared__ float wred[8];
  __shared__ float pG[2][3][512];
  int b = blockIdx.x, t = threadIdx.x;
  int lane = t & 63, wave = t >> 6;
  int u = t & 511, hf = t >> 9;
  int len = lens[b];
  float bhr = 0, bhz = 0, bhn = 0, bcu = 0;
  if (t < 512) {
    bhr = bhh[u]; bhz = bhh[512 + u]; bhn = bhh[1024 + u]; bcu = bc[u];
    hs[u] = h_init[b * 512 + u];
  }
  __syncthreads();
  const float4* EOb = (const float4*)(EO + (long)b * 128 * 512);

  for (int step = 0; step < STEPS_; ++step) {
    // ---- attention scores: wave w handles s = w*8 .. w*8+7 ----
    float4 h1 = ((const float4*)hs)[lane * 2];
    float4 h2 = ((const float4*)hs)[lane * 2 + 1];
    for (int si = 0; si < 8; ++si) {
      int s = wave * 8 + si;
      const float4* er = EOb + (long)s * 128;
      float4 e1 = er[lane * 2], e2 = er[lane * 2 + 1];
      float p = e1.x * h1.x + e1.y * h1.y + e1.z * h1.z + e1.w * h1.w +
                e2.x * h2.x + e2.y * h2.y + e2.z * h2.z + e2.w * h2.w;
#pragma unroll
      for (int off = 32; off > 0; off >>= 1) p += __shfl_down(p, off, 64);
      if (lane == 0) sc[s] = p;
    }
    __syncthreads();
    // ---- softmax over s<len (threads 0..127 == waves 0..1) ----
    float v = (t < 128) ? ((t < len) ? sc[t] : -INFINITY) : -INFINITY;
    float wm = v;
#pragma unroll
    for (int off = 32; off > 0; off >>= 1) wm = fmaxf(wm, __shfl_down(wm, off, 64));
    if (lane == 0 && wave < 2) wred[wave] = wm;
    __syncthreads();
    float m = fmaxf(wred[0], wred[1]);
    float e = (t < 128 && t < len) ? expf(sc[t] - m) : 0.f;
    float esum = e;
#pragma unroll
    for (int off = 32; off > 0; off >>= 1) esum += __shfl_down(esum, off, 64);
    if (lane == 0 && wave < 2) wred[4 + wave] = esum;
    __syncthreads();
    float ssum = wred[4] + wred[5];
    if (t < 128) {
      float aw = e / ssum;
      sc[t] = aw;
      attns[((long)b * STEPS_ + step) * 128 + t] = aw;
    }
    __syncthreads();
    // ---- ctx[u] = sum_s aw[s]*EO[b][s][u], s split across halves ----
    {
      float acc = 0.f;
      const float* eo = EO + (long)b * 128 * 512 + (long)hf * 64 * 512 + u;
#pragma unroll 8
      for (int s2 = 0; s2 < 64; ++s2) acc += sc[hf * 64 + s2] * eo[(long)s2 * 512];
      pG[hf][0][u] = acc;
    }
    __syncthreads();
    if (t < 512) cs[u] = pG[0][0][u] + pG[1][0][u];
    __syncthreads();
    // ---- gates: hf=0 -> Whh x hs ; hf=1 -> Wih_ctx x cs ----
    {
      const __half2* RZ = hf ? RZc : RZh;
      const __half* Np = hf ? Nc : Nh;
      const float* xv = hf ? cs : hs;
      float ar = 0.f, az = 0.f, an = 0.f;
#pragma unroll 8
      for (int k = 0; k < 512; ++k) {
        float xk = xv[k];
        float2 rz = __half22float2(RZ[k * 512 + u]);
        float wn = __half2float(Np[k * 512 + u]);
        ar += xk * rz.x; az += xk * rz.y; an += xk * wn;
      }
      pG[hf][0][u] = ar; pG[hf][1][u] = az; pG[hf][2][u] = an;
    }
    __syncthreads();
    if (t < 512) {
      const float* gi = gie + ((long)step * 32 + b) * 1536;
      float r = 1.f / (1.f + expf(-(gi[u] + pG[1][0][u] + pG[0][0][u] + bhr)));
      float z = 1.f / (1.f + expf(-(gi[512 + u] + pG[1][1][u] + pG[0][1][u] + bhz)));
      float n = tanhf(gi[1024 + u] + pG[1][2][u] + r * (pG[0][2][u] + bhn));
      hs[u] = (1.f - z) * n + z * hs[u];
    }
    __syncthreads();
    // ---- cc = tanh([hn, ctx] @ Wc^T + bc), k split across halves ----
    {
      const float* xv = hf ? cs : hs;
      const __half2* wp = WcP + (long)(hf * 256) * 512 + u;
      float c = 0.f;
#pragma unroll 8
      for (int kk = 0; kk < 256; ++kk) {
        float2 wv = __half22float2(wp[(long)kk * 512]);
        c += xv[2 * kk] * wv.x + xv[2 * kk + 1] * wv.y;
      }
      pG[hf][0][u] = c;
    }
    __syncthreads();
    if (t < 512) ccall[((long)step * 32 + b) * 512 + u] = tanhf(pG[0][0][u] + pG[1][0][u] + bcu);
    __syncthreads();
  }
}

extern "C" void kernel_launch(void* const* d_in, const int* in_sizes, int n_in,
                              void* d_out, int out_size, void* d_ws, size_t ws_size,
                              hipStream_t stream) {
  (void)in_sizes; (void)n_in; (void)out_size; (void)ws_size;
  const int*   src   = (const int*)d_in[0];
  const int*   lens  = (const int*)d_in[1];
  const int*   tgt   = (const int*)d_in[2];
  const float* emb_e = (const float*)d_in[3];
  const float* Wih_e = (const float*)d_in[4];
  const float* Whh_e = (const float*)d_in[5];
  const float* bih_e = (const float*)d_in[6];
  const float* bhh_e = (const float*)d_in[7];
  const float* emb_d = (const float*)d_in[8];
  const float* Wih_d = (const float*)d_in[9];
  const float* Whh_d = (const float*)d_in[10];
  const float* bih_d = (const float*)d_in[11];
  const float* bhh_d = (const float*)d_in[12];
  const float* Wc    = (const float*)d_in[13];
  const float* bc    = (const float*)d_in[14];
  const float* Wo    = (const float*)d_in[15];
  const float* bo    = (const float*)d_in[16];

  float* logits = (float*)d_out;
  float* attns  = (float*)d_out + (long)B_ * STEPS_ * V_;

  float* w = (float*)d_ws;
  __half2* RZ_e  = (__half2*)w;                 // 512*512 half2 (1MB)
  __half*  N_e   = (__half*)(w + 262144);       // 512KB
  __half2* RZ_hd = (__half2*)(w + 393216);
  __half*  N_hd  = (__half*)(w + 655360);
  __half2* RZ_cd = (__half2*)(w + 786432);
  __half*  N_cd  = (__half*)(w + 1048576);
  __half2* WcP   = (__half2*)(w + 1179648);     // 1MB
  float* GIe   = w + 1441792;                   // 4096 x 1536
  float* GId   = GIe + 6291456;                 // 2048 x 1536 (pad)
  float* EO    = GId + 3145728;                 // 32 x 128 x 512
  float* h0    = EO + 2097152;                  // 32 x 512
  float* ccall = h0 + 16384;                    // 2016 x 512

  k_pack_rzn<<<1024, 256, 0, stream>>>(Whh_e, 512, 0, RZ_e, N_e);
  k_pack_rzn<<<1024, 256, 0, stream>>>(Whh_d, 512, 0, RZ_hd, N_hd);
  k_pack_rzn<<<1024, 256, 0, stream>>>(Wih_d, 1024, 512, RZ_cd, N_cd);
  k_pack_wc<<<1024, 256, 0, stream>>>(Wc, WcP);

  // GIe[s*32+b][:] = emb_enc[src[b,s]] @ Wih_e^T + bih_e   (B = Wih_e, k-major)
  k_mfma_gemm<<<dim3(1536 / 128, 4096 / 128), 256, 0, stream>>>(
      nullptr, emb_e, src, 1, Wih_e, 512, bih_e, GIe, 1536L, 32L * 1536L, 4096, 1536, 512);
  // GId[t*32+b][:] = emb_dec[tgt[b,t]] @ Wih_d[:, :512]^T + bih_d  (ldb=1024)
  k_mfma_gemm<<<dim3(1536 / 128, (2016 + 127) / 128), 256, 0, stream>>>(
      nullptr, emb_d, tgt, 2, Wih_d, 1024, bih_d, GId, 1536L, 32L * 1536L, 2016, 1536, 512);

  k_enc_all<<<32, 1024, 0, stream>>>(GIe, RZ_e, N_e, bhh_e, lens, h0, EO);

  k_dec_all<<<32, 1024, 0, stream>>>(GId, EO, RZ_hd, N_hd, RZ_cd, N_cd, WcP,
                                     bhh_d, bc, lens, h0, ccall, attns);

  // logits: A = ccall [2016][512], B = Wo [32000][512] (k-major)
  k_mfma_gemm<<<dim3(V_ / 128, (2016 + 127) / 128), 256, 0, stream>>>(
      ccall, nullptr, nullptr, 0, Wo, 512, bo, logits,
      (long)STEPS_ * V_, (long)V_, 2016, 32000, 512);
}

// Round 7
// 4805.577 us; speedup vs baseline: 3.5930x; 3.5930x over previous
//
#include <hip/hip_runtime.h>
#include <hip/hip_fp16.h>
#include <cmath>

#define B_ 32
#define S_ 128
#define T_ 64
#define STEPS_ 63
#define V_ 32000
#define E_ 512
#define H_ 512

typedef __attribute__((ext_vector_type(4))) float f32x4;
typedef __attribute__((ext_vector_type(8))) short bf16x8;
typedef __attribute__((ext_vector_type(2))) _Float16 f16x2;

__device__ inline short f2bf(float x) {
  unsigned u = __builtin_bit_cast(unsigned, x);
  u = (u + 0x7fffu + ((u >> 16) & 1u)) >> 16;
  return (short)u;
}
__device__ inline float bf2f(short h) {
  unsigned u = ((unsigned)(unsigned short)h) << 16;
  return __builtin_bit_cast(float, u);
}

__device__ inline float fdot2(__half2 a, __half2 b, float c) {
#if __has_builtin(__builtin_amdgcn_fdot2)
  return __builtin_amdgcn_fdot2(__builtin_bit_cast(f16x2, a),
                                __builtin_bit_cast(f16x2, b), c, false);
#else
  float2 af = __half22float2(a), bf = __half22float2(b);
  return c + af.x * bf.x + af.y * bf.y;
#endif
}

// ---- pack GRU trio into k-paired f16 streams --------------------------------
// RZ2[kk*512+u] = float2{ bits(half2(Wr[2kk][u],Wr[2kk+1][u])),
//                         bits(half2(Wz[2kk][u],Wz[2kk+1][u])) }
// N2[kk*512+u]  = half2(Wn[2kk][u], Wn[2kk+1][u])
// W is [1536][ldw]; gate rows r=u, z=512+u, n=1024+u; k col = col0+k.
__global__ __launch_bounds__(256) void k_pack_rzn(
    const float* __restrict__ W, int ldw, int col0,
    float2* __restrict__ RZ2, __half2* __restrict__ N2) {
  int idx = blockIdx.x * 256 + threadIdx.x;  // 131072 = 256 kk * 512 u
  int kk = idx >> 9, u = idx & 511;
  long k0 = col0 + 2 * kk;
  __half2 r2 = __halves2half2(__float2half(W[(long)u * ldw + k0]),
                              __float2half(W[(long)u * ldw + k0 + 1]));
  __half2 z2 = __halves2half2(__float2half(W[(long)(512 + u) * ldw + k0]),
                              __float2half(W[(long)(512 + u) * ldw + k0 + 1]));
  __half2 n2 = __halves2half2(__float2half(W[(long)(1024 + u) * ldw + k0]),
                              __float2half(W[(long)(1024 + u) * ldw + k0 + 1]));
  float2 rz;
  ((__half2*)&rz)[0] = r2;
  ((__half2*)&rz)[1] = z2;
  RZ2[idx] = rz;
  N2[idx] = n2;
}

// ---- MFMA bf16 split-precision GEMM (R1/R2-proven; + act flag) --------------
__global__ __launch_bounds__(256) void k_mfma_gemm(
    const float* __restrict__ A, const float* __restrict__ emb,
    const int* __restrict__ tok, int amode,
    const float* __restrict__ Bmat, long ldb,
    const float* __restrict__ bias,
    float* __restrict__ out, long sb, long st,
    int M, int N, int K, int act) {
  __shared__ short Ah[128 * 40];
  __shared__ short Al[128 * 40];
  __shared__ short Bh[128 * 40];
  __shared__ short Bl[128 * 40];
  int t = threadIdx.x;
  int n0 = blockIdx.x * 128, m0 = blockIdx.y * 128;
  int ar = t >> 2, ac = (t & 3) * 8;

  const float* arow0;
  const float* arow1;
  {
    int m = m0 + ar;       int mc = m < M ? m : M - 1;
    int m2 = m0 + ar + 64; int mc2 = m2 < M ? m2 : M - 1;
    if (amode == 0) {
      arow0 = A + (long)mc * K;
      arow1 = A + (long)mc2 * K;
    } else {
      int b = mc & 31, q = mc >> 5;
      int tk = (amode == 1) ? tok[b * S_ + q] : tok[b * T_ + q];
      arow0 = emb + (long)tk * K;
      b = mc2 & 31; q = mc2 >> 5;
      tk = (amode == 1) ? tok[b * S_ + q] : tok[b * T_ + q];
      arow1 = emb + (long)tk * K;
    }
  }
  const float* brow0 = Bmat + (long)(n0 + ar) * ldb;
  const float* brow1 = Bmat + (long)(n0 + ar + 64) * ldb;

  int lane = t & 63, wave = t >> 6;
  int wm = (wave >> 1) * 64, wn = (wave & 1) * 64;
  int lr = lane & 15, lk = lane >> 4;
  f32x4 acc[4][4] = {};

  for (int k0 = 0; k0 < K; k0 += 32) {
    auto stage = [&](const float* rowp, short* Dh, short* Dl, int r) {
      float4 x0 = *(const float4*)(rowp + k0 + ac);
      float4 x1 = *(const float4*)(rowp + k0 + ac + 4);
      float xs[8] = {x0.x, x0.y, x0.z, x0.w, x1.x, x1.y, x1.z, x1.w};
      bf16x8 hi, lo;
#pragma unroll
      for (int i = 0; i < 8; ++i) {
        short h = f2bf(xs[i]);
        hi[i] = h;
        lo[i] = f2bf(xs[i] - bf2f(h));
      }
      *(bf16x8*)&Dh[r * 40 + ac] = hi;
      *(bf16x8*)&Dl[r * 40 + ac] = lo;
    };
    stage(arow0, Ah, Al, ar);
    stage(arow1, Ah, Al, ar + 64);
    stage(brow0, Bh, Bl, ar);
    stage(brow1, Bh, Bl, ar + 64);
    __syncthreads();

    bf16x8 a_h[4], a_l[4], b_h[4], b_l[4];
#pragma unroll
    for (int i = 0; i < 4; ++i) {
      int ra = (wm + i * 16 + lr) * 40 + lk * 8;
      a_h[i] = *(const bf16x8*)&Ah[ra];
      a_l[i] = *(const bf16x8*)&Al[ra];
      int rb = (wn + i * 16 + lr) * 40 + lk * 8;
      b_h[i] = *(const bf16x8*)&Bh[rb];
      b_l[i] = *(const bf16x8*)&Bl[rb];
    }
#pragma unroll
    for (int i = 0; i < 4; ++i)
#pragma unroll
      for (int j = 0; j < 4; ++j) {
        acc[i][j] = __builtin_amdgcn_mfma_f32_16x16x32_bf16(a_l[i], b_h[j], acc[i][j], 0, 0, 0);
        acc[i][j] = __builtin_amdgcn_mfma_f32_16x16x32_bf16(a_h[i], b_l[j], acc[i][j], 0, 0, 0);
        acc[i][j] = __builtin_amdgcn_mfma_f32_16x16x32_bf16(a_h[i], b_h[j], acc[i][j], 0, 0, 0);
      }
    __syncthreads();
  }

#pragma unroll
  for (int i = 0; i < 4; ++i) {
#pragma unroll
    for (int r = 0; r < 4; ++r) {
      int m = m0 + wm + i * 16 + lk * 4 + r;
      if (m >= M) continue;
      long base = (long)(m & 31) * sb + (long)(m >> 5) * st;
#pragma unroll
      for (int j = 0; j < 4; ++j) {
        int n = n0 + wn + j * 16 + lr;
        float v = acc[i][j][r] + bias[n];
        out[base + n] = act ? tanhf(v) : v;
      }
    }
  }
}

// ---- encoder: 32 blocks x 1024 threads; dot2 gates; EO16 output -------------
__global__ __launch_bounds__(1024) void k_enc_all(
    const float* __restrict__ gi_all,      // [S*B][1536], row = s*32+b (bih folded)
    const float2* __restrict__ RZ2, const __half2* __restrict__ N2,
    const float* __restrict__ bhh, const int* __restrict__ lens,
    float* __restrict__ h_out, __half* __restrict__ EO16) {
  __shared__ __align__(16) float hs[512];
  __shared__ __align__(16) __half2 hs16[256];
  __shared__ float pG[4][3][512];
  int b = blockIdx.x, t = threadIdx.x;
  int j = t & 255, grp = t >> 8;       // grp = k-quarter, j = u-pair
  int u0 = 2 * j;
  int len = lens[b];
  float bhr0 = 0, bhr1 = 0, bhz0 = 0, bhz1 = 0, bhn0 = 0, bhn1 = 0;
  if (t < 256) {
    bhr0 = bhh[u0]; bhr1 = bhh[u0 + 1];
    bhz0 = bhh[512 + u0]; bhz1 = bhh[512 + u0 + 1];
    bhn0 = bhh[1024 + u0]; bhn1 = bhh[1024 + u0 + 1];
  }
  if (t < 512) hs[t] = 0.f;
  if (t < 256) hs16[t] = __float22half2_rn(make_float2(0.f, 0.f));
  __syncthreads();
  int kk0 = grp * 64;

  for (int s = 0; s < S_; ++s) {
    float ar0 = 0, az0 = 0, an0 = 0, ar1 = 0, az1 = 0, an1 = 0;
#pragma unroll 8
    for (int kk = kk0; kk < kk0 + 64; ++kk) {
      __half2 x2 = hs16[kk];
      float4 rz = *(const float4*)(RZ2 + (long)kk * 512 + u0);
      __half2 r2a = ((__half2*)&rz)[0], z2a = ((__half2*)&rz)[1];
      __half2 r2b = ((__half2*)&rz)[2], z2b = ((__half2*)&rz)[3];
      float2 nn = *(const float2*)(N2 + (long)kk * 512 + u0);
      __half2 n2a = ((__half2*)&nn)[0], n2b = ((__half2*)&nn)[1];
      ar0 = fdot2(x2, r2a, ar0); az0 = fdot2(x2, z2a, az0); an0 = fdot2(x2, n2a, an0);
      ar1 = fdot2(x2, r2b, ar1); az1 = fdot2(x2, z2b, az1); an1 = fdot2(x2, n2b, an1);
    }
    pG[grp][0][u0] = ar0; pG[grp][0][u0 + 1] = ar1;
    pG[grp][1][u0] = az0; pG[grp][1][u0 + 1] = az1;
    pG[grp][2][u0] = an0; pG[grp][2][u0 + 1] = an1;
    __syncthreads();
    if (t < 256) {
      const float* gi = gi_all + ((long)s * 32 + b) * 1536;
      bool valid = s < len;
      float hn2[2];
#pragma unroll
      for (int q = 0; q < 2; ++q) {
        int u = u0 + q;
        float AR = pG[0][0][u] + pG[1][0][u] + pG[2][0][u] + pG[3][0][u] + (q ? bhr1 : bhr0);
        float AZ = pG[0][1][u] + pG[1][1][u] + pG[2][1][u] + pG[3][1][u] + (q ? bhz1 : bhz0);
        float AN = pG[0][2][u] + pG[1][2][u] + pG[2][2][u] + pG[3][2][u] + (q ? bhn1 : bhn0);
        float r = 1.f / (1.f + expf(-(gi[u] + AR)));
        float z = 1.f / (1.f + expf(-(gi[512 + u] + AZ)));
        float n = tanhf(gi[1024 + u] + r * AN);
        float hold = hs[u];
        float hn = (1.f - z) * n + z * hold;
        hn2[q] = valid ? hn : hold;
        hs[u] = hn2[q];
      }
      hs16[j] = __float22half2_rn(make_float2(hn2[0], hn2[1]));
      *(__half2*)(EO16 + ((long)b * 128 + s) * 512 + u0) =
          valid ? __float22half2_rn(make_float2(hn2[0], hn2[1]))
                : __float22half2_rn(make_float2(0.f, 0.f));
    }
    __syncthreads();
  }
  if (t < 512) h_out[b * 512 + t] = hs[t];
}

// ---- decoder: 32 blocks x 1024 threads; EO in LDS; cc deferred --------------
__global__ __launch_bounds__(1024) void k_dec_all(
    const float* __restrict__ gie,         // [STEPS*B][1536], row = t*32+b
    const __half* __restrict__ EO16g,      // [32][128][512]
    const float2* __restrict__ RZ2h, const __half2* __restrict__ N2h,   // Whh_d
    const float2* __restrict__ RZ2c, const __half2* __restrict__ N2c,   // Wih_d ctx
    const float* __restrict__ bhh, const int* __restrict__ lens,
    const float* __restrict__ h_init,
    float* __restrict__ hctx,              // [2048 pad][1024]: [0:512]=hn, [512:1024]=ctx
    float* __restrict__ attns) {
  __shared__ __align__(16) __half2 EO[128][256];   // 128 KB
  __shared__ __align__(16) float hs[512];
  __shared__ __align__(16) __half2 hs16[256];
  __shared__ __align__(16) __half2 cs16[256];
  __shared__ float pG[4][3][512];
  __shared__ float sc[128];
  __shared__ float wred[8];
  int b = blockIdx.x, t = threadIdx.x;
  int lane = t & 63, wave = t >> 6;
  int j = t & 255, grp = t >> 8;   // gates: grp = {mat,kh}; ctx: grp = s-quarter
  int u0 = 2 * j;
  int len = lens[b];
  float bhr0 = 0, bhr1 = 0, bhz0 = 0, bhz1 = 0, bhn0 = 0, bhn1 = 0;
  if (t < 256) {
    bhr0 = bhh[u0]; bhr1 = bhh[u0 + 1];
    bhz0 = bhh[512 + u0]; bhz1 = bhh[512 + u0 + 1];
    bhn0 = bhh[1024 + u0]; bhn1 = bhh[1024 + u0 + 1];
  }
  // stage EO16 -> LDS
  {
    const uint4* src = (const uint4*)(EO16g + (long)b * 128 * 512);
    uint4* dst = (uint4*)&EO[0][0];
    for (int i = t; i < 8192; i += 1024) dst[i] = src[i];
  }
  if (t < 512) hs[t] = h_init[b * 512 + t];
  __syncthreads();
  if (t < 256) hs16[t] = __float22half2_rn(make_float2(hs[2 * t], hs[2 * t + 1]));
  __syncthreads();

  int mat = grp >> 1, kh = grp & 1;
  const float2* RZp = mat ? RZ2c : RZ2h;
  const __half2* Np = mat ? N2c : N2h;
  int kk0 = kh * 128;

  for (int step = 0; step < STEPS_; ++step) {
    // ---- attention scores: wave w -> s = w*8..w*8+7 (from LDS, f16) ----
    uint4 hv = *(const uint4*)&hs16[lane * 4];
    __half2* hvp = (__half2*)&hv;
    for (int si = 0; si < 8; ++si) {
      int s = wave * 8 + si;
      uint4 ev = *(const uint4*)&EO[s][lane * 4];
      __half2* evp = (__half2*)&ev;
      float p = 0.f;
#pragma unroll
      for (int q = 0; q < 4; ++q) p = fdot2(evp[q], hvp[q], p);
#pragma unroll
      for (int off = 32; off > 0; off >>= 1) p += __shfl_down(p, off, 64);
      if (lane == 0) sc[s] = p;
    }
    __syncthreads();
    // ---- softmax over s<len ----
    float v = (t < 128) ? ((t < len) ? sc[t] : -INFINITY) : -INFINITY;
    float wm = v;
#pragma unroll
    for (int off = 32; off > 0; off >>= 1) wm = fmaxf(wm, __shfl_down(wm, off, 64));
    if (lane == 0 && wave < 2) wred[wave] = wm;
    __syncthreads();
    float m = fmaxf(wred[0], wred[1]);
    float e = (t < 128 && t < len) ? expf(sc[t] - m) : 0.f;
    float esum = e;
#pragma unroll
    for (int off = 32; off > 0; off >>= 1) esum += __shfl_down(esum, off, 64);
    if (lane == 0 && wave < 2) wred[4 + wave] = esum;
    __syncthreads();
    float ssum = wred[4] + wred[5];
    if (t < 128) {
      float aw = e / ssum;
      sc[t] = aw;
      attns[((long)b * STEPS_ + step) * 128 + t] = aw;
    }
    __syncthreads();
    // ---- ctx partials: grp = s-quarter, thread j -> units u0,u0+1 ----
    {
      float a0 = 0.f, a1 = 0.f;
      int sbase = grp * 32;
#pragma unroll 8
      for (int s2 = 0; s2 < 32; ++s2) {
        float awv = sc[sbase + s2];
        float2 ef = __half22float2(EO[sbase + s2][j]);
        a0 += awv * ef.x;
        a1 += awv * ef.y;
      }
      pG[grp][0][u0] = a0;
      pG[grp][0][u0 + 1] = a1;
    }
    __syncthreads();
    if (t < 256) {
      float c0 = pG[0][0][u0] + pG[1][0][u0] + pG[2][0][u0] + pG[3][0][u0];
      float c1 = pG[0][0][u0 + 1] + pG[1][0][u0 + 1] + pG[2][0][u0 + 1] + pG[3][0][u0 + 1];
      cs16[j] = __float22half2_rn(make_float2(c0, c1));
      float* row = hctx + ((long)step * 32 + b) * 1024 + 512;
      row[u0] = c0;
      row[u0 + 1] = c1;
    }
    __syncthreads();
    // ---- gates: mat 0 = Whh x h, mat 1 = Wih_ctx x ctx; kh halves of k ----
    {
      const __half2* xv = mat ? cs16 : hs16;
      float ar0 = 0, az0 = 0, an0 = 0, ar1 = 0, az1 = 0, an1 = 0;
#pragma unroll 8
      for (int kk = kk0; kk < kk0 + 128; ++kk) {
        __half2 x2 = xv[kk];
        float4 rz = *(const float4*)(RZp + (long)kk * 512 + u0);
        __half2 r2a = ((__half2*)&rz)[0], z2a = ((__half2*)&rz)[1];
        __half2 r2b = ((__half2*)&rz)[2], z2b = ((__half2*)&rz)[3];
        float2 nn = *(const float2*)(Np + (long)kk * 512 + u0);
        __half2 n2a = ((__half2*)&nn)[0], n2b = ((__half2*)&nn)[1];
        ar0 = fdot2(x2, r2a, ar0); az0 = fdot2(x2, z2a, az0); an0 = fdot2(x2, n2a, an0);
        ar1 = fdot2(x2, r2b, ar1); az1 = fdot2(x2, z2b, az1); an1 = fdot2(x2, n2b, an1);
      }
      pG[grp][0][u0] = ar0; pG[grp][0][u0 + 1] = ar1;
      pG[grp][1][u0] = az0; pG[grp][1][u0 + 1] = az1;
      pG[grp][2][u0] = an0; pG[grp][2][u0 + 1] = an1;
    }
    __syncthreads();
    if (t < 256) {
      const float* gi = gie + ((long)step * 32 + b) * 1536;
      float* row = hctx + ((long)step * 32 + b) * 1024;
      float hn2[2];
#pragma unroll
      for (int q = 0; q < 2; ++q) {
        int u = u0 + q;
        float rh = pG[0][0][u] + pG[1][0][u], rc = pG[2][0][u] + pG[3][0][u];
        float zh = pG[0][1][u] + pG[1][1][u], zc = pG[2][1][u] + pG[3][1][u];
        float nh = pG[0][2][u] + pG[1][2][u], nc = pG[2][2][u] + pG[3][2][u];
        float r = 1.f / (1.f + expf(-(gi[u] + rc + rh + (q ? bhr1 : bhr0))));
        float z = 1.f / (1.f + expf(-(gi[512 + u] + zc + zh + (q ? bhz1 : bhz0))));
        float n = tanhf(gi[1024 + u] + nc + r * (nh + (q ? bhn1 : bhn0)));
        float hn = (1.f - z) * n + z * hs[u];
        hs[u] = hn;
        row[u] = hn;
        hn2[q] = hn;
      }
      hs16[j] = __float22half2_rn(make_float2(hn2[0], hn2[1]));
    }
    __syncthreads();
  }
}

extern "C" void kernel_launch(void* const* d_in, const int* in_sizes, int n_in,
                              void* d_out, int out_size, void* d_ws, size_t ws_size,
                              hipStream_t stream) {
  (void)in_sizes; (void)n_in; (void)out_size; (void)ws_size;
  const int*   src   = (const int*)d_in[0];
  const int*   lens  = (const int*)d_in[1];
  const int*   tgt   = (const int*)d_in[2];
  const float* emb_e = (const float*)d_in[3];
  const float* Wih_e = (const float*)d_in[4];
  const float* Whh_e = (const float*)d_in[5];
  const float* bih_e = (const float*)d_in[6];
  const float* bhh_e = (const float*)d_in[7];
  const float* emb_d = (const float*)d_in[8];
  const float* Wih_d = (const float*)d_in[9];
  const float* Whh_d = (const float*)d_in[10];
  const float* bih_d = (const float*)d_in[11];
  const float* bhh_d = (const float*)d_in[12];
  const float* Wc    = (const float*)d_in[13];
  const float* bc    = (const float*)d_in[14];
  const float* Wo    = (const float*)d_in[15];
  const float* bo    = (const float*)d_in[16];

  float* logits = (float*)d_out;
  float* attns  = (float*)d_out + (long)B_ * STEPS_ * V_;

  float* w = (float*)d_ws;
  float2*  RZ2_e  = (float2*)w;                    // 131072 float2 = 1MB
  __half2* N2_e   = (__half2*)(w + 262144);        // 512KB
  float2*  RZ2_hd = (float2*)(w + 393216);
  __half2* N2_hd  = (__half2*)(w + 655360);
  float2*  RZ2_cd = (float2*)(w + 786432);
  __half2* N2_cd  = (__half2*)(w + 1048576);
  float* GIe   = w + 1179648;                      // 4096 x 1536
  float* GId   = GIe + 6291456;                    // 2048 x 1536 (pad)
  __half* EO16 = (__half*)(GId + 3145728);         // 32*128*512 halves (4MB)
  float* h0    = GId + 3145728 + 1048576;          // 32 x 512
  float* hctx  = h0 + 16384;                       // 2048 x 1024
  float* ccall = hctx + 2097152;                   // 2016 x 512

  k_pack_rzn<<<512, 256, 0, stream>>>(Whh_e, 512, 0, RZ2_e, N2_e);
  k_pack_rzn<<<512, 256, 0, stream>>>(Whh_d, 512, 0, RZ2_hd, N2_hd);
  k_pack_rzn<<<512, 256, 0, stream>>>(Wih_d, 1024, 512, RZ2_cd, N2_cd);

  // GIe[s*32+b][:] = emb_enc[src[b,s]] @ Wih_e^T + bih_e
  k_mfma_gemm<<<dim3(1536 / 128, 4096 / 128), 256, 0, stream>>>(
      nullptr, emb_e, src, 1, Wih_e, 512, bih_e, GIe, 1536L, 32L * 1536L,
      4096, 1536, 512, 0);
  // GId[t*32+b][:] = emb_dec[tgt[b,t]] @ Wih_d[:, :512]^T + bih_d
  k_mfma_gemm<<<dim3(1536 / 128, (2016 + 127) / 128), 256, 0, stream>>>(
      nullptr, emb_d, tgt, 2, Wih_d, 1024, bih_d, GId, 1536L, 32L * 1536L,
      2016, 1536, 512, 0);

  k_enc_all<<<32, 1024, 0, stream>>>(GIe, RZ2_e, N2_e, bhh_e, lens, h0, EO16);

  k_dec_all<<<32, 1024, 0, stream>>>(GId, EO16, RZ2_hd, N2_hd, RZ2_cd, N2_cd,
                                     bhh_d, lens, h0, hctx, attns);

  // cc = tanh([hn|ctx] @ Wc^T + bc): A = hctx [2016][1024], B = Wc [512][1024]
  k_mfma_gemm<<<dim3(512 / 128, (2016 + 127) / 128), 256, 0, stream>>>(
      hctx, nullptr, nullptr, 0, Wc, 1024, bc, ccall, 512L, 16384L,
      2016, 512, 1024, 1);

  // logits: A = ccall [2016][512], B = Wo [32000][512]
  k_mfma_gemm<<<dim3(V_ / 128, (2016 + 127) / 128), 256, 0, stream>>>(
      ccall, nullptr, nullptr, 0, Wo, 512, bo, logits,
      (long)STEPS_ * V_, (long)V_, 2016, 32000, 512, 0);
}

// Round 8
// 4570.187 us; speedup vs baseline: 3.7780x; 1.0515x over previous
//
#include <hip/hip_runtime.h>
#include <hip/hip_fp16.h>
#include <cmath>

#define B_ 32
#define S_ 128
#define T_ 64
#define STEPS_ 63
#define V_ 32000
#define E_ 512
#define H_ 512

typedef __attribute__((ext_vector_type(4))) float f32x4;
typedef __attribute__((ext_vector_type(8))) short bf16x8;
typedef __attribute__((ext_vector_type(2))) _Float16 f16x2;

__device__ inline short f2bf(float x) {
  unsigned u = __builtin_bit_cast(unsigned, x);
  u = (u + 0x7fffu + ((u >> 16) & 1u)) >> 16;
  return (short)u;
}
__device__ inline float bf2f(short h) {
  unsigned u = ((unsigned)(unsigned short)h) << 16;
  return __builtin_bit_cast(float, u);
}
__device__ inline float fdot2(__half2 a, __half2 b, float c) {
#if __has_builtin(__builtin_amdgcn_fdot2)
  return __builtin_amdgcn_fdot2(__builtin_bit_cast(f16x2, a),
                                __builtin_bit_cast(f16x2, b), c, false);
#else
  float2 af = __half22float2(a), bf = __half22float2(b);
  return c + af.x * bf.x + af.y * bf.y;
#endif
}
__device__ inline float sigm(float x) { return 1.f / (1.f + expf(-x)); }

// ---- pack GRU weight trio [1536][512] f32 -> f16 stream -------------------
// halves[ ((kq*3+g)*256+up)*8 + q*2+ui ] = W[(g*512+2up+ui)*512 + 4kq+q]
__global__ __launch_bounds__(256) void k_pack_w3(
    const float* __restrict__ W, __half* __restrict__ W3) {
  int idx = blockIdx.x * 256 + threadIdx.x;   // 98304 = 128 kq * 3 g * 256 up
  int up = idx & 255, g = (idx >> 8) % 3, kq = idx / 768;
  __half h[8];
#pragma unroll
  for (int q = 0; q < 4; ++q)
#pragma unroll
    for (int ui = 0; ui < 2; ++ui)
      h[q * 2 + ui] = __float2half(W[(long)(g * 512 + 2 * up + ui) * 512 + 4 * kq + q]);
  *(uint4*)(W3 + (long)idx * 8) = *(uint4*)h;
}

// ---- MFMA bf16 split-precision GEMM; outmode: 0 f32, 1 f32+tanh, 2 f16 ----
__global__ __launch_bounds__(256) void k_mfma_gemm(
    const float* __restrict__ A, const float* __restrict__ emb,
    const int* __restrict__ tok, int amode,
    const float* __restrict__ Bmat, long ldb,
    const float* __restrict__ bias,
    void* __restrict__ outp, long sb, long st,
    int M, int N, int K, int outmode) {
  __shared__ short Ah[128 * 40];
  __shared__ short Al[128 * 40];
  __shared__ short Bh[128 * 40];
  __shared__ short Bl[128 * 40];
  int t = threadIdx.x;
  int n0 = blockIdx.x * 128, m0 = blockIdx.y * 128;
  int ar = t >> 2, ac = (t & 3) * 8;

  const float* arow0;
  const float* arow1;
  {
    int m = m0 + ar;       int mc = m < M ? m : M - 1;
    int m2 = m0 + ar + 64; int mc2 = m2 < M ? m2 : M - 1;
    if (amode == 0) {
      arow0 = A + (long)mc * K;
      arow1 = A + (long)mc2 * K;
    } else {
      int b = mc & 31, q = mc >> 5;
      int tk = (amode == 1) ? tok[b * S_ + q] : tok[b * T_ + q];
      arow0 = emb + (long)tk * K;
      b = mc2 & 31; q = mc2 >> 5;
      tk = (amode == 1) ? tok[b * S_ + q] : tok[b * T_ + q];
      arow1 = emb + (long)tk * K;
    }
  }
  const float* brow0 = Bmat + (long)(n0 + ar) * ldb;
  const float* brow1 = Bmat + (long)(n0 + ar + 64) * ldb;

  int lane = t & 63, wave = t >> 6;
  int wm = (wave >> 1) * 64, wn = (wave & 1) * 64;
  int lr = lane & 15, lk = lane >> 4;
  f32x4 acc[4][4] = {};

  for (int k0 = 0; k0 < K; k0 += 32) {
    auto stage = [&](const float* rowp, short* Dh, short* Dl, int r) {
      float4 x0 = *(const float4*)(rowp + k0 + ac);
      float4 x1 = *(const float4*)(rowp + k0 + ac + 4);
      float xs[8] = {x0.x, x0.y, x0.z, x0.w, x1.x, x1.y, x1.z, x1.w};
      bf16x8 hi, lo;
#pragma unroll
      for (int i = 0; i < 8; ++i) {
        short h = f2bf(xs[i]);
        hi[i] = h;
        lo[i] = f2bf(xs[i] - bf2f(h));
      }
      *(bf16x8*)&Dh[r * 40 + ac] = hi;
      *(bf16x8*)&Dl[r * 40 + ac] = lo;
    };
    stage(arow0, Ah, Al, ar);
    stage(arow1, Ah, Al, ar + 64);
    stage(brow0, Bh, Bl, ar);
    stage(brow1, Bh, Bl, ar + 64);
    __syncthreads();

    bf16x8 a_h[4], a_l[4], b_h[4], b_l[4];
#pragma unroll
    for (int i = 0; i < 4; ++i) {
      int ra = (wm + i * 16 + lr) * 40 + lk * 8;
      a_h[i] = *(const bf16x8*)&Ah[ra];
      a_l[i] = *(const bf16x8*)&Al[ra];
      int rb = (wn + i * 16 + lr) * 40 + lk * 8;
      b_h[i] = *(const bf16x8*)&Bh[rb];
      b_l[i] = *(const bf16x8*)&Bl[rb];
    }
#pragma unroll
    for (int i = 0; i < 4; ++i)
#pragma unroll
      for (int j = 0; j < 4; ++j) {
        acc[i][j] = __builtin_amdgcn_mfma_f32_16x16x32_bf16(a_l[i], b_h[j], acc[i][j], 0, 0, 0);
        acc[i][j] = __builtin_amdgcn_mfma_f32_16x16x32_bf16(a_h[i], b_l[j], acc[i][j], 0, 0, 0);
        acc[i][j] = __builtin_amdgcn_mfma_f32_16x16x32_bf16(a_h[i], b_h[j], acc[i][j], 0, 0, 0);
      }
    __syncthreads();
  }

#pragma unroll
  for (int i = 0; i < 4; ++i) {
#pragma unroll
    for (int r = 0; r < 4; ++r) {
      int m = m0 + wm + i * 16 + lk * 4 + r;
      if (m >= M) continue;
      long base = (long)(m & 31) * sb + (long)(m >> 5) * st;
#pragma unroll
      for (int j = 0; j < 4; ++j) {
        int n = n0 + wn + j * 16 + lr;
        float v = acc[i][j][r] + bias[n];
        if (outmode == 2) ((__half*)outp)[base + n] = __float2half(v);
        else ((float*)outp)[base + n] = (outmode == 1) ? tanhf(v) : v;
      }
    }
  }
}

// ---- encoder: 32 blocks x 1024 thr; waves 4-15 stream W3e; early-break ----
__global__ __launch_bounds__(1024) void k_enc_all(
    const float* __restrict__ gi_all,      // [S*B][1536], row = s*32+b (bih folded)
    const __half* __restrict__ W3,         // packed Whh_e
    const float* __restrict__ bhh, const int* __restrict__ lens,
    float* __restrict__ h_out,
    __half* __restrict__ EO16,             // [32][128][512] (pre-zeroed)
    float* __restrict__ EO32) {            // [4096][512]   (pre-zeroed)
  __shared__ __align__(16) float hs[512];
  __shared__ __align__(8) __half2 hs16[256];
  __shared__ float pGh[1536];
  int b = blockIdx.x, t = threadIdx.x;
  int len = lens[b];
  float br0 = 0, br1 = 0, bz0 = 0, bz1 = 0, bn0 = 0, bn1 = 0;
  if (t < 256) {
    br0 = bhh[2 * t]; br1 = bhh[2 * t + 1];
    bz0 = bhh[512 + 2 * t]; bz1 = bhh[512 + 2 * t + 1];
    bn0 = bhh[1024 + 2 * t]; bn1 = bhh[1024 + 2 * t + 1];
  }
  if (t < 512) hs[t] = 0.f;
  if (t < 256) hs16[t] = __float22half2_rn(make_float2(0.f, 0.f));
  __syncthreads();

  for (int s = 0; s < S_; ++s) {
    if (s == len) break;
    if (t >= 256) {
      int c = t - 256, g = c >> 8, up = c & 255;
      float a0 = 0.f, a1 = 0.f;
#pragma unroll 8
      for (int kq = 0; kq < 128; ++kq) {
        uint4 w8 = *(const uint4*)(W3 + ((long)(kq * 3 + g) * 256 + up) * 8);
        const __half2* wp = (const __half2*)&w8;
#pragma unroll
        for (int q = 0; q < 4; ++q) {
          float2 xf = __half22float2(hs16[2 * kq + (q >> 1)]);
          float xk = (q & 1) ? xf.y : xf.x;
          float2 wf = __half22float2(wp[q]);
          a0 += xk * wf.x;
          a1 += xk * wf.y;
        }
      }
      pGh[g * 512 + 2 * up] = a0;
      pGh[g * 512 + 2 * up + 1] = a1;
    }
    __syncthreads();
    if (t < 256) {
      const float* gi = gi_all + ((long)s * 32 + b) * 1536;
      int u0 = 2 * t;
      float2 gr = *(const float2*)(gi + u0);
      float2 gz = *(const float2*)(gi + 512 + u0);
      float2 gn = *(const float2*)(gi + 1024 + u0);
      float r0 = sigm(gr.x + pGh[u0] + br0);
      float r1 = sigm(gr.y + pGh[u0 + 1] + br1);
      float z0 = sigm(gz.x + pGh[512 + u0] + bz0);
      float z1 = sigm(gz.y + pGh[512 + u0 + 1] + bz1);
      float n0 = tanhf(gn.x + r0 * (pGh[1024 + u0] + bn0));
      float n1 = tanhf(gn.y + r1 * (pGh[1024 + u0 + 1] + bn1));
      float h0 = (1.f - z0) * n0 + z0 * hs[u0];
      float h1 = (1.f - z1) * n1 + z1 * hs[u0 + 1];
      hs[u0] = h0; hs[u0 + 1] = h1;
      hs16[t] = __float22half2_rn(make_float2(h0, h1));
      long row = (long)b * 128 + s;
      *(__half2*)(EO16 + row * 512 + u0) = hs16[t];
      *(float2*)(EO32 + row * 512 + u0) = make_float2(h0, h1);
    }
    __syncthreads();
  }
  if (t < 512) h_out[b * 512 + t] = hs[t];
}

// ---- decoder: 32 blocks x 1024 thr; wave0 att+ctx || waves4-15 Whh stream ----
__global__ __launch_bounds__(1024) void k_dec_all(
    const float* __restrict__ gie,         // [STEPS*B][1536], row = t*32+b
    const __half* __restrict__ EO16g,      // [32][128][512]
    const __half* __restrict__ W3,         // packed Whh_d
    const __half* __restrict__ GV,         // [4096][1536] f16, row = b*128+s
    const float* __restrict__ bhh, const int* __restrict__ lens,
    const float* __restrict__ h_init,
    float* __restrict__ hctx,              // [2016+][1024]: [0:512]=hn [512:1024]=ctx
    float* __restrict__ attns) {
  __shared__ __align__(16) __half2 EOs[32768];   // 128 KB, swizzled: [s*256 + (c^(s&31))]
  __shared__ __align__(16) float hs[512];
  __shared__ __align__(8) __half2 hs16[256];
  __shared__ float pGh[1536];
  __shared__ float pGc[1536];
  __shared__ float sc[128];
  int b = blockIdx.x, t = threadIdx.x;
  int lane = t & 63;
  int len = lens[b];
  float br0 = 0, br1 = 0, bz0 = 0, bz1 = 0, bn0 = 0, bn1 = 0;
  if (t < 256) {
    br0 = bhh[2 * t]; br1 = bhh[2 * t + 1];
    bz0 = bhh[512 + 2 * t]; bz1 = bhh[512 + 2 * t + 1];
    bn0 = bhh[1024 + 2 * t]; bn1 = bhh[1024 + 2 * t + 1];
  }
  // stage EO16 -> LDS with XOR swizzle
  {
    const __half2* src = (const __half2*)(EO16g + (long)b * 128 * 512);
    for (int i = t; i < 32768; i += 1024) {
      int s = i >> 8, c = i & 255;
      EOs[s * 256 + (c ^ (s & 31))] = src[i];
    }
  }
  if (t < 512) hs[t] = h_init[b * 512 + t];
  __syncthreads();
  if (t < 256) hs16[t] = __float22half2_rn(make_float2(hs[2 * t], hs[2 * t + 1]));
  __syncthreads();
  const __half2* GVb = (const __half2*)GV + (long)b * 128 * 768;

  for (int step = 0; step < STEPS_; ++step) {
    long row = (long)step * 32 + b;
    if (t < 64) {
      // ---- scores for s = lane and s = 64+lane ----
      float p0 = 0.f, p1 = 0.f;
      int x0 = lane & 31;
      const __half2* e0 = &EOs[lane * 256];
      const __half2* e1 = &EOs[(64 + lane) * 256];
#pragma unroll 8
      for (int c = 0; c < 256; ++c) {
        __half2 h2 = hs16[c];
        p0 = fdot2(e0[c ^ x0], h2, p0);
        p1 = fdot2(e1[c ^ x0], h2, p1);
      }
      bool v0 = lane < len, v1 = 64 + lane < len;
      float m = fmaxf(v0 ? p0 : -INFINITY, v1 ? p1 : -INFINITY);
#pragma unroll
      for (int off = 32; off > 0; off >>= 1) m = fmaxf(m, __shfl_xor(m, off, 64));
      float e0v = v0 ? expf(p0 - m) : 0.f;
      float e1v = v1 ? expf(p1 - m) : 0.f;
      float S = e0v + e1v;
#pragma unroll
      for (int off = 32; off > 0; off >>= 1) S += __shfl_xor(S, off, 64);
      float aw0 = e0v / S, aw1 = e1v / S;
      sc[lane] = aw0;
      sc[64 + lane] = aw1;
      float* ap = attns + ((long)b * STEPS_ + step) * 128;
      ap[lane] = aw0;
      ap[64 + lane] = aw1;
      // ---- ctx-gates (GV weighted sum) + ctx ----
      float cgx[12] = {}, cgy[12] = {};
      float cxx[4] = {}, cxy[4] = {};
      for (int s = 0; s < 128; ++s) {
        if (s == len) break;
        float aw = sc[s];
        const __half2* gv = GVb + (long)s * 768;
#pragma unroll
        for (int i = 0; i < 12; ++i) {
          float2 g2 = __half22float2(gv[lane + 64 * i]);
          cgx[i] += aw * g2.x;
          cgy[i] += aw * g2.y;
        }
        const __half2* er = &EOs[s * 256];
        int xs = s & 31;
#pragma unroll
        for (int i = 0; i < 4; ++i) {
          float2 e2 = __half22float2(er[(lane + 64 * i) ^ xs]);
          cxx[i] += aw * e2.x;
          cxy[i] += aw * e2.y;
        }
      }
#pragma unroll
      for (int i = 0; i < 12; ++i) {
        int col = lane + 64 * i;
        pGc[2 * col] = cgx[i];
        pGc[2 * col + 1] = cgy[i];
      }
      float* crow = hctx + row * 1024 + 512;
#pragma unroll
      for (int i = 0; i < 4; ++i) {
        int col = lane + 64 * i;
        *(float2*)(crow + 2 * col) = make_float2(cxx[i], cxy[i]);
      }
    } else if (t >= 256) {
      // ---- h-gates: stream W3 (Whh_d) ----
      int c = t - 256, g = c >> 8, up = c & 255;
      float a0 = 0.f, a1 = 0.f;
#pragma unroll 8
      for (int kq = 0; kq < 128; ++kq) {
        uint4 w8 = *(const uint4*)(W3 + ((long)(kq * 3 + g) * 256 + up) * 8);
        const __half2* wp = (const __half2*)&w8;
#pragma unroll
        for (int q = 0; q < 4; ++q) {
          float2 xf = __half22float2(hs16[2 * kq + (q >> 1)]);
          float xk = (q & 1) ? xf.y : xf.x;
          float2 wf = __half22float2(wp[q]);
          a0 += xk * wf.x;
          a1 += xk * wf.y;
        }
      }
      pGh[g * 512 + 2 * up] = a0;
      pGh[g * 512 + 2 * up + 1] = a1;
    }
    __syncthreads();
    // ---- cell ----
    if (t < 256) {
      const float* gi = gie + row * 1536;
      int u0 = 2 * t;
      float2 gr = *(const float2*)(gi + u0);
      float2 gz = *(const float2*)(gi + 512 + u0);
      float2 gn = *(const float2*)(gi + 1024 + u0);
      float r0 = sigm(gr.x + pGc[u0] + pGh[u0] + br0);
      float r1 = sigm(gr.y + pGc[u0 + 1] + pGh[u0 + 1] + br1);
      float z0 = sigm(gz.x + pGc[512 + u0] + pGh[512 + u0] + bz0);
      float z1 = sigm(gz.y + pGc[512 + u0 + 1] + pGh[512 + u0 + 1] + bz1);
      float n0 = tanhf(gn.x + pGc[1024 + u0] + r0 * (pGh[1024 + u0] + bn0));
      float n1 = tanhf(gn.y + pGc[1024 + u0 + 1] + r1 * (pGh[1024 + u0 + 1] + bn1));
      float h0 = (1.f - z0) * n0 + z0 * hs[u0];
      float h1 = (1.f - z1) * n1 + z1 * hs[u0 + 1];
      hs[u0] = h0; hs[u0 + 1] = h1;
      hs16[t] = __float22half2_rn(make_float2(h0, h1));
      *(float2*)(hctx + row * 1024 + u0) = make_float2(h0, h1);
    }
    __syncthreads();
  }
}

extern "C" void kernel_launch(void* const* d_in, const int* in_sizes, int n_in,
                              void* d_out, int out_size, void* d_ws, size_t ws_size,
                              hipStream_t stream) {
  (void)in_sizes; (void)n_in; (void)out_size; (void)ws_size;
  const int*   src   = (const int*)d_in[0];
  const int*   lens  = (const int*)d_in[1];
  const int*   tgt   = (const int*)d_in[2];
  const float* emb_e = (const float*)d_in[3];
  const float* Wih_e = (const float*)d_in[4];
  const float* Whh_e = (const float*)d_in[5];
  const float* bih_e = (const float*)d_in[6];
  const float* bhh_e = (const float*)d_in[7];
  const float* emb_d = (const float*)d_in[8];
  const float* Wih_d = (const float*)d_in[9];
  const float* Whh_d = (const float*)d_in[10];
  const float* bih_d = (const float*)d_in[11];
  const float* bhh_d = (const float*)d_in[12];
  const float* Wc    = (const float*)d_in[13];
  const float* bc    = (const float*)d_in[14];
  const float* Wo    = (const float*)d_in[15];
  const float* bo    = (const float*)d_in[16];

  float* logits = (float*)d_out;
  float* attns  = (float*)d_out + (long)B_ * STEPS_ * V_;

  float* w = (float*)d_ws;
  __half* W3e  = (__half*)w;                    // 786432 halves (1.5MB)
  __half* W3d  = (__half*)(w + 393216);         // 1.5MB
  float*  zb   = w + 786432;                    // 1536 zeros (GV bias)
  float*  GIe  = w + 788480;                    // 4096 x 1536 f32
  float*  GId  = GIe + 6291456;                 // 2048 x 1536 f32
  __half* EO16 = (__half*)(GId + 3145728);      // 2097152 halves (4MB)
  float*  EO32 = GId + 3145728 + 1048576;       // 4096 x 512 f32 (8MB)
  float*  h0   = EO32 + 2097152;                // 32 x 512
  // overlays inside GIe (dead after encoder):
  __half* GV    = (__half*)GIe;                 // 4096 x 1536 f16 (12.6MB)
  float*  hctx  = GIe + 3145728;                // 2048 x 1024 f32 (8.4MB)
  float*  ccall = GIe + 5242880;                // 2016 x 512 f32 (4.1MB)

  hipMemsetAsync(EO16, 0, 2097152 * sizeof(__half), stream);
  hipMemsetAsync(EO32, 0, 2097152 * sizeof(float), stream);
  hipMemsetAsync(zb, 0, 1536 * sizeof(float), stream);

  k_pack_w3<<<384, 256, 0, stream>>>(Whh_e, W3e);
  k_pack_w3<<<384, 256, 0, stream>>>(Whh_d, W3d);

  // GIe[s*32+b][:] = emb_enc[src[b,s]] @ Wih_e^T + bih_e
  k_mfma_gemm<<<dim3(1536 / 128, 4096 / 128), 256, 0, stream>>>(
      nullptr, emb_e, src, 1, Wih_e, 512, bih_e, GIe, 1536L, 32L * 1536L,
      4096, 1536, 512, 0);
  // GId[t*32+b][:] = emb_dec[tgt[b,t]] @ Wih_d[:, :512]^T + bih_d
  k_mfma_gemm<<<dim3(1536 / 128, (2016 + 127) / 128), 256, 0, stream>>>(
      nullptr, emb_d, tgt, 2, Wih_d, 1024, bih_d, GId, 1536L, 32L * 1536L,
      2016, 1536, 512, 0);

  k_enc_all<<<32, 1024, 0, stream>>>(GIe, W3e, bhh_e, lens, h0, EO16, EO32);

  // GV[b*128+s][n] = EO32[b*128+s] @ Wih_d[:,512:1024]^T  (f16 out, zero bias)
  k_mfma_gemm<<<dim3(1536 / 128, 4096 / 128), 256, 0, stream>>>(
      EO32, nullptr, nullptr, 0, Wih_d + 512, 1024, zb, GV, 1536L, 49152L,
      4096, 1536, 512, 2);

  k_dec_all<<<32, 1024, 0, stream>>>(GId, EO16, W3d, GV, bhh_d, lens, h0,
                                     hctx, attns);

  // cc = tanh([hn|ctx] @ Wc^T + bc)
  k_mfma_gemm<<<dim3(512 / 128, (2016 + 127) / 128), 256, 0, stream>>>(
      hctx, nullptr, nullptr, 0, Wc, 1024, bc, ccall, 512L, 16384L,
      2016, 512, 1024, 1);

  // logits = ccall @ Wo^T + bo
  k_mfma_gemm<<<dim3(V_ / 128, (2016 + 127) / 128), 256, 0, stream>>>(
      ccall, nullptr, nullptr, 0, Wo, 512, bo, logits,
      (long)STEPS_ * V_, (long)V_, 2016, 32000, 512, 0);
}

// Round 9
// 3426.031 us; speedup vs baseline: 5.0398x; 1.3340x over previous
//
#include <hip/hip_runtime.h>
#include <hip/hip_fp16.h>
#include <cmath>

#define B_ 32
#define S_ 128
#define T_ 64
#define STEPS_ 63
#define V_ 32000
#define E_ 512
#define H_ 512

typedef __attribute__((ext_vector_type(4))) float f32x4;
typedef __attribute__((ext_vector_type(8))) short bf16x8;
typedef __attribute__((ext_vector_type(2))) _Float16 f16x2;

__device__ inline short f2bf(float x) {
  unsigned u = __builtin_bit_cast(unsigned, x);
  u = (u + 0x7fffu + ((u >> 16) & 1u)) >> 16;
  return (short)u;
}
__device__ inline float bf2f(short h) {
  unsigned u = ((unsigned)(unsigned short)h) << 16;
  return __builtin_bit_cast(float, u);
}
__device__ inline float fdot2(__half2 a, __half2 b, float c) {
#if __has_builtin(__builtin_amdgcn_fdot2)
  return __builtin_amdgcn_fdot2(__builtin_bit_cast(f16x2, a),
                                __builtin_bit_cast(f16x2, b), c, false);
#else
  float2 af = __half22float2(a), bf = __half22float2(b);
  return c + af.x * bf.x + af.y * bf.y;
#endif
}
__device__ inline float sigm(float x) { return 1.f / (1.f + expf(-x)); }

// ---- pack GRU weight trio -> k-paired f16 stream for fdot2 ------------------
// item (kq,g,up): 4 half2 = {(k0,k1)@u0, (k0,k1)@u1, (k2,k3)@u0, (k2,k3)@u1}
// W rows: gate-major (g*512+u), k col = col0+k, row stride ldw.
__global__ __launch_bounds__(256) void k_pack_w3(
    const float* __restrict__ W, int ldw, int col0, __half* __restrict__ W3) {
  int idx = blockIdx.x * 256 + threadIdx.x;   // 98304 = 128 kq * 3 g * 256 up
  int up = idx & 255, g = (idx >> 8) % 3, kq = idx / 768;
  const float* r0 = W + (long)(g * 512 + 2 * up) * ldw + col0 + 4 * kq;
  const float* r1 = r0 + ldw;
  __half h[8];
  h[0] = __float2half(r0[0]); h[1] = __float2half(r0[1]);
  h[2] = __float2half(r1[0]); h[3] = __float2half(r1[1]);
  h[4] = __float2half(r0[2]); h[5] = __float2half(r0[3]);
  h[6] = __float2half(r1[2]); h[7] = __float2half(r1[3]);
  *(uint4*)(W3 + (long)idx * 8) = *(uint4*)h;
}

// ---- MFMA bf16 split GEMM; outmode: 0 f32, 1 f32+tanh, 2 f16; passes 1|3 ----
__global__ __launch_bounds__(256) void k_mfma_gemm(
    const float* __restrict__ A, const float* __restrict__ emb,
    const int* __restrict__ tok, int amode,
    const float* __restrict__ Bmat, long ldb,
    const float* __restrict__ bias,
    void* __restrict__ outp, long sb, long st,
    int M, int N, int K, int outmode, int passes) {
  __shared__ short Ah[128 * 40];
  __shared__ short Al[128 * 40];
  __shared__ short Bh[128 * 40];
  __shared__ short Bl[128 * 40];
  int t = threadIdx.x;
  int n0 = blockIdx.x * 128, m0 = blockIdx.y * 128;
  int ar = t >> 2, ac = (t & 3) * 8;

  const float* arow0;
  const float* arow1;
  {
    int m = m0 + ar;       int mc = m < M ? m : M - 1;
    int m2 = m0 + ar + 64; int mc2 = m2 < M ? m2 : M - 1;
    if (amode == 0) {
      arow0 = A + (long)mc * K;
      arow1 = A + (long)mc2 * K;
    } else {
      int b = mc & 31, q = mc >> 5;
      int tk = (amode == 1) ? tok[b * S_ + q] : tok[b * T_ + q];
      arow0 = emb + (long)tk * K;
      b = mc2 & 31; q = mc2 >> 5;
      tk = (amode == 1) ? tok[b * S_ + q] : tok[b * T_ + q];
      arow1 = emb + (long)tk * K;
    }
  }
  const float* brow0 = Bmat + (long)(n0 + ar) * ldb;
  const float* brow1 = Bmat + (long)(n0 + ar + 64) * ldb;

  int lane = t & 63, wave = t >> 6;
  int wm = (wave >> 1) * 64, wn = (wave & 1) * 64;
  int lr = lane & 15, lk = lane >> 4;
  f32x4 acc[4][4] = {};

  for (int k0 = 0; k0 < K; k0 += 32) {
    auto stage = [&](const float* rowp, short* Dh, short* Dl, int r) {
      float4 x0 = *(const float4*)(rowp + k0 + ac);
      float4 x1 = *(const float4*)(rowp + k0 + ac + 4);
      float xs[8] = {x0.x, x0.y, x0.z, x0.w, x1.x, x1.y, x1.z, x1.w};
      bf16x8 hi, lo;
#pragma unroll
      for (int i = 0; i < 8; ++i) {
        short h = f2bf(xs[i]);
        hi[i] = h;
        lo[i] = f2bf(xs[i] - bf2f(h));
      }
      *(bf16x8*)&Dh[r * 40 + ac] = hi;
      if (passes > 1) *(bf16x8*)&Dl[r * 40 + ac] = lo;
    };
    stage(arow0, Ah, Al, ar);
    stage(arow1, Ah, Al, ar + 64);
    stage(brow0, Bh, Bl, ar);
    stage(brow1, Bh, Bl, ar + 64);
    __syncthreads();

    bf16x8 a_h[4], b_h[4];
#pragma unroll
    for (int i = 0; i < 4; ++i) {
      a_h[i] = *(const bf16x8*)&Ah[(wm + i * 16 + lr) * 40 + lk * 8];
      b_h[i] = *(const bf16x8*)&Bh[(wn + i * 16 + lr) * 40 + lk * 8];
    }
    if (passes > 1) {
      bf16x8 a_l[4], b_l[4];
#pragma unroll
      for (int i = 0; i < 4; ++i) {
        a_l[i] = *(const bf16x8*)&Al[(wm + i * 16 + lr) * 40 + lk * 8];
        b_l[i] = *(const bf16x8*)&Bl[(wn + i * 16 + lr) * 40 + lk * 8];
      }
#pragma unroll
      for (int i = 0; i < 4; ++i)
#pragma unroll
        for (int j = 0; j < 4; ++j) {
          acc[i][j] = __builtin_amdgcn_mfma_f32_16x16x32_bf16(a_l[i], b_h[j], acc[i][j], 0, 0, 0);
          acc[i][j] = __builtin_amdgcn_mfma_f32_16x16x32_bf16(a_h[i], b_l[j], acc[i][j], 0, 0, 0);
        }
    }
#pragma unroll
    for (int i = 0; i < 4; ++i)
#pragma unroll
      for (int j = 0; j < 4; ++j)
        acc[i][j] = __builtin_amdgcn_mfma_f32_16x16x32_bf16(a_h[i], b_h[j], acc[i][j], 0, 0, 0);
    __syncthreads();
  }

#pragma unroll
  for (int i = 0; i < 4; ++i) {
#pragma unroll
    for (int r = 0; r < 4; ++r) {
      int m = m0 + wm + i * 16 + lk * 4 + r;
      if (m >= M) continue;
      long base = (long)(m & 31) * sb + (long)(m >> 5) * st;
#pragma unroll
      for (int j = 0; j < 4; ++j) {
        int n = n0 + wn + j * 16 + lr;
        float v = acc[i][j][r] + bias[n];
        if (outmode == 2) ((__half*)outp)[base + n] = __float2half(v);
        else ((float*)outp)[base + n] = (outmode == 1) ? tanhf(v) : v;
      }
    }
  }
}

// ---- encoder: 32 blocks x 1024 thr; 768-thr fdot2 stream; reg-resident h ----
__global__ __launch_bounds__(1024) void k_enc_all(
    const float* __restrict__ gi_all,      // [S*B][1536], row = s*32+b (bih folded)
    const __half* __restrict__ W3,         // packed Whh_e
    const float* __restrict__ bhh, const int* __restrict__ lens,
    float* __restrict__ h_out,
    __half* __restrict__ EO16,             // [32][128][512] (pre-zeroed)
    float* __restrict__ EO32) {            // [4096][512]    (pre-zeroed)
  __shared__ __align__(8) __half2 hs16[256];
  __shared__ float pGh[1536];
  __shared__ float gis[1536];
  int b = blockIdx.x, t = threadIdx.x;
  int len = lens[b];
  float br0 = 0, br1 = 0, bz0 = 0, bz1 = 0, bn0 = 0, bn1 = 0, hold0 = 0, hold1 = 0;
  if (t < 256) {
    br0 = bhh[2 * t]; br1 = bhh[2 * t + 1];
    bz0 = bhh[512 + 2 * t]; bz1 = bhh[512 + 2 * t + 1];
    bn0 = bhh[1024 + 2 * t]; bn1 = bhh[1024 + 2 * t + 1];
    hs16[t] = __float22half2_rn(make_float2(0.f, 0.f));
  }
  __syncthreads();

  for (int s = 0; s < S_; ++s) {
    if (s == len) break;
    if (t >= 256) {
      int c = t - 256, g = c >> 8, up = c & 255;
      const __half* wb = W3 + (long)(g * 256 + up) * 8;
      float a0 = 0.f, a1 = 0.f;
#pragma unroll 8
      for (int kq = 0; kq < 128; ++kq) {
        uint4 w8 = *(const uint4*)(wb + (long)kq * 6144);
        const __half2* wp = (const __half2*)&w8;
        __half2 x01 = hs16[2 * kq], x23 = hs16[2 * kq + 1];
        a0 = fdot2(x01, wp[0], a0); a1 = fdot2(x01, wp[1], a1);
        a0 = fdot2(x23, wp[2], a0); a1 = fdot2(x23, wp[3], a1);
      }
      pGh[g * 512 + 2 * up] = a0;
      pGh[g * 512 + 2 * up + 1] = a1;
    } else {
      const float* gi = gi_all + ((long)s * 32 + b) * 1536;
      int i0 = t * 6;
#pragma unroll
      for (int i = 0; i < 6; ++i) gis[i0 + i] = gi[i0 + i];
    }
    __syncthreads();
    if (t < 256) {
      int u0 = 2 * t;
      float r0 = sigm(gis[u0] + pGh[u0] + br0);
      float r1 = sigm(gis[u0 + 1] + pGh[u0 + 1] + br1);
      float z0 = sigm(gis[512 + u0] + pGh[512 + u0] + bz0);
      float z1 = sigm(gis[512 + u0 + 1] + pGh[512 + u0 + 1] + bz1);
      float n0 = tanhf(gis[1024 + u0] + r0 * (pGh[1024 + u0] + bn0));
      float n1 = tanhf(gis[1024 + u0 + 1] + r1 * (pGh[1024 + u0 + 1] + bn1));
      hold0 = (1.f - z0) * n0 + z0 * hold0;
      hold1 = (1.f - z1) * n1 + z1 * hold1;
      __half2 h2 = __float22half2_rn(make_float2(hold0, hold1));
      hs16[t] = h2;
      long row = (long)b * 128 + s;
      *(__half2*)(EO16 + row * 512 + u0) = h2;
      *(float2*)(EO32 + row * 512 + u0) = make_float2(hold0, hold1);
    }
    __syncthreads();
  }
  if (t < 256) *(float2*)(h_out + b * 512 + 2 * t) = make_float2(hold0, hold1);
}

// ---- decoder: 32 blocks x 1024 thr; 4-phase balanced step -------------------
__global__ __launch_bounds__(1024) void k_dec_all(
    const float* __restrict__ gie,         // [STEPS*B][1536], row = t*32+b
    const __half* __restrict__ EO16g,      // [32][128][512]
    const __half* __restrict__ W3,         // packed Whh_d
    const __half* __restrict__ GV,         // [4096][1536] f16, row = b*128+s
    const float* __restrict__ bhh, const int* __restrict__ lens,
    const float* __restrict__ h_init,
    float* __restrict__ hctx,              // [2016+][1024]: [0:512]=hn [512:1024]=ctx
    float* __restrict__ attns) {
  __shared__ __align__(16) __half2 EOs[32768];   // 128 KB, linear [s][c]
  __shared__ __align__(8) __half2 hs16[256];
  __shared__ float pGh[1536];
  __shared__ float pGc[1536];
  __shared__ float gis[1536];
  __shared__ float sc[128];
  __shared__ float wred[8];
  int b = blockIdx.x, t = threadIdx.x;
  int lane = t & 63, wave = t >> 6;
  int len = lens[b];
  float br0 = 0, br1 = 0, bz0 = 0, bz1 = 0, bn0 = 0, bn1 = 0, hold0 = 0, hold1 = 0;
  if (t < 256) {
    br0 = bhh[2 * t]; br1 = bhh[2 * t + 1];
    bz0 = bhh[512 + 2 * t]; bz1 = bhh[512 + 2 * t + 1];
    bn0 = bhh[1024 + 2 * t]; bn1 = bhh[1024 + 2 * t + 1];
    float2 h2 = *(const float2*)(h_init + b * 512 + 2 * t);
    hold0 = h2.x; hold1 = h2.y;
    hs16[t] = __float22half2_rn(h2);
  }
  // stage EO16 -> LDS (linear)
  {
    const uint4* src = (const uint4*)(EO16g + (long)b * 128 * 512);
    uint4* dst = (uint4*)EOs;
    for (int i = t; i < 8192; i += 1024) dst[i] = src[i];
  }
  __syncthreads();
  const __half2* GVb = (const __half2*)GV + (long)b * 128 * 768;

  for (int step = 0; step < STEPS_; ++step) {
    long row = (long)step * 32 + b;
    // ---- A: scores, wave w -> s = w*8..w*8+7, wave-wide dot ----
    {
      uint4 hv = ((const uint4*)hs16)[lane];
      const __half2* hp = (const __half2*)&hv;
#pragma unroll
      for (int si = 0; si < 8; ++si) {
        int s = wave * 8 + si;
        uint4 ev = ((const uint4*)&EOs[s * 256])[lane];
        const __half2* ep = (const __half2*)&ev;
        float p = 0.f;
#pragma unroll
        for (int q = 0; q < 4; ++q) p = fdot2(ep[q], hp[q], p);
#pragma unroll
        for (int off = 32; off > 0; off >>= 1) p += __shfl_down(p, off, 64);
        if (lane == 0) sc[s] = p;
      }
    }
    __syncthreads();
    // ---- B: softmax (t<128) || gis prefetch (t in [128,512)) ----
    if (t < 128) {
      float v = (t < len) ? sc[t] : -INFINITY;
      float wm = v;
#pragma unroll
      for (int off = 32; off > 0; off >>= 1) wm = fmaxf(wm, __shfl_down(wm, off, 64));
      if (lane == 0) wred[wave] = wm;
    } else if (t < 512) {
      const float* gi = gie + row * 1536;
      int i0 = (t - 128) * 4;
      *(float4*)(gis + i0) = *(const float4*)(gi + i0);
    }
    __syncthreads();
    if (t < 128) {
      float m = fmaxf(wred[0], wred[1]);
      float e = (t < len) ? expf(sc[t] - m) : 0.f;
      float es = e;
#pragma unroll
      for (int off = 32; off > 0; off >>= 1) es += __shfl_down(es, off, 64);
      if (lane == 0) wred[4 + wave] = es;
      __syncthreads();
      float aw = e / (wred[4] + wred[5]);
      sc[t] = aw;
      attns[((long)b * STEPS_ + step) * 128 + t] = aw;
    } else {
      __syncthreads();
    }
    __syncthreads();
    // ---- C||D: W3 stream (t<768) || GV/ctx weighted sum (t>=768) ----
    if (t < 768) {
      int g = t >> 8, up = t & 255;
      const __half* wb = W3 + (long)(g * 256 + up) * 8;
      float a0 = 0.f, a1 = 0.f;
#pragma unroll 8
      for (int kq = 0; kq < 128; ++kq) {
        uint4 w8 = *(const uint4*)(wb + (long)kq * 6144);
        const __half2* wp = (const __half2*)&w8;
        __half2 x01 = hs16[2 * kq], x23 = hs16[2 * kq + 1];
        a0 = fdot2(x01, wp[0], a0); a1 = fdot2(x01, wp[1], a1);
        a0 = fdot2(x23, wp[2], a0); a1 = fdot2(x23, wp[3], a1);
      }
      pGh[g * 512 + 2 * up] = a0;
      pGh[g * 512 + 2 * up + 1] = a1;
    } else if (t < 960) {
      // GV: 192 threads x 4 half2-cols
      int c4 = (t - 768) * 4;
      float ax0 = 0, ay0 = 0, ax1 = 0, ay1 = 0, ax2 = 0, ay2 = 0, ax3 = 0, ay3 = 0;
#pragma unroll 2
      for (int s = 0; s < 128; ++s) {
        if (s == len) break;
        float aw = sc[s];
        uint4 g4 = *(const uint4*)(GVb + (long)s * 768 + c4);
        const __half2* gp = (const __half2*)&g4;
        float2 f0 = __half22float2(gp[0]), f1 = __half22float2(gp[1]);
        float2 f2 = __half22float2(gp[2]), f3 = __half22float2(gp[3]);
        ax0 += aw * f0.x; ay0 += aw * f0.y;
        ax1 += aw * f1.x; ay1 += aw * f1.y;
        ax2 += aw * f2.x; ay2 += aw * f2.y;
        ax3 += aw * f3.x; ay3 += aw * f3.y;
      }
      pGc[2 * c4 + 0] = ax0; pGc[2 * c4 + 1] = ay0;
      pGc[2 * c4 + 2] = ax1; pGc[2 * c4 + 3] = ay1;
      pGc[2 * c4 + 4] = ax2; pGc[2 * c4 + 5] = ay2;
      pGc[2 * c4 + 6] = ax3; pGc[2 * c4 + 7] = ay3;
    } else {
      // ctx: 64 threads x 4 half2-cols from EOs LDS
      int ec = (t - 960) * 4;
      float ax0 = 0, ay0 = 0, ax1 = 0, ay1 = 0, ax2 = 0, ay2 = 0, ax3 = 0, ay3 = 0;
#pragma unroll 2
      for (int s = 0; s < 128; ++s) {
        if (s == len) break;
        float aw = sc[s];
        uint4 e4 = ((const uint4*)&EOs[s * 256])[t - 960];
        const __half2* ep = (const __half2*)&e4;
        float2 f0 = __half22float2(ep[0]), f1 = __half22float2(ep[1]);
        float2 f2 = __half22float2(ep[2]), f3 = __half22float2(ep[3]);
        ax0 += aw * f0.x; ay0 += aw * f0.y;
        ax1 += aw * f1.x; ay1 += aw * f1.y;
        ax2 += aw * f2.x; ay2 += aw * f2.y;
        ax3 += aw * f3.x; ay3 += aw * f3.y;
      }
      float* crow = hctx + row * 1024 + 512 + 2 * ec;
      *(float2*)(crow + 0) = make_float2(ax0, ay0);
      *(float2*)(crow + 2) = make_float2(ax1, ay1);
      *(float2*)(crow + 4) = make_float2(ax2, ay2);
      *(float2*)(crow + 6) = make_float2(ax3, ay3);
    }
    __syncthreads();
    // ---- E: cell (t<256) ----
    if (t < 256) {
      int u0 = 2 * t;
      float r0 = sigm(gis[u0] + pGc[u0] + pGh[u0] + br0);
      float r1 = sigm(gis[u0 + 1] + pGc[u0 + 1] + pGh[u0 + 1] + br1);
      float z0 = sigm(gis[512 + u0] + pGc[512 + u0] + pGh[512 + u0] + bz0);
      float z1 = sigm(gis[512 + u0 + 1] + pGc[512 + u0 + 1] + pGh[512 + u0 + 1] + bz1);
      float n0 = tanhf(gis[1024 + u0] + pGc[1024 + u0] + r0 * (pGh[1024 + u0] + bn0));
      float n1 = tanhf(gis[1024 + u0 + 1] + pGc[1024 + u0 + 1] + r1 * (pGh[1024 + u0 + 1] + bn1));
      hold0 = (1.f - z0) * n0 + z0 * hold0;
      hold1 = (1.f - z1) * n1 + z1 * hold1;
      hs16[t] = __float22half2_rn(make_float2(hold0, hold1));
      *(float2*)(hctx + row * 1024 + u0) = make_float2(hold0, hold1);
    }
    __syncthreads();
  }
}

extern "C" void kernel_launch(void* const* d_in, const int* in_sizes, int n_in,
                              void* d_out, int out_size, void* d_ws, size_t ws_size,
                              hipStream_t stream) {
  (void)in_sizes; (void)n_in; (void)out_size; (void)ws_size;
  const int*   src   = (const int*)d_in[0];
  const int*   lens  = (const int*)d_in[1];
  const int*   tgt   = (const int*)d_in[2];
  const float* emb_e = (const float*)d_in[3];
  const float* Wih_e = (const float*)d_in[4];
  const float* Whh_e = (const float*)d_in[5];
  const float* bih_e = (const float*)d_in[6];
  const float* bhh_e = (const float*)d_in[7];
  const float* emb_d = (const float*)d_in[8];
  const float* Wih_d = (const float*)d_in[9];
  const float* Whh_d = (const float*)d_in[10];
  const float* bih_d = (const float*)d_in[11];
  const float* bhh_d = (const float*)d_in[12];
  const float* Wc    = (const float*)d_in[13];
  const float* bc    = (const float*)d_in[14];
  const float* Wo    = (const float*)d_in[15];
  const float* bo    = (const float*)d_in[16];

  float* logits = (float*)d_out;
  float* attns  = (float*)d_out + (long)B_ * STEPS_ * V_;

  float* w = (float*)d_ws;
  __half* W3e  = (__half*)w;                    // 786432 halves (1.5MB)
  __half* W3d  = (__half*)(w + 393216);         // 1.5MB
  float*  zb   = w + 786432;                    // 1536 zeros (GV bias)
  float*  GIe  = w + 788480;                    // 4096 x 1536 f32
  float*  GId  = GIe + 6291456;                 // 2048 x 1536 f32
  __half* EO16 = (__half*)(GId + 3145728);      // 4MB
  float*  EO32 = GId + 3145728 + 1048576;       // 8MB
  float*  h0   = EO32 + 2097152;                // 32 x 512
  // overlays inside GIe (dead after encoder):
  __half* GV    = (__half*)GIe;                 // 4096 x 1536 f16
  float*  hctx  = GIe + 3145728;                // 2048 x 1024 f32
  float*  ccall = GIe + 5242880;                // 2016 x 512 f32

  hipMemsetAsync(EO16, 0, 2097152 * sizeof(__half), stream);
  hipMemsetAsync(EO32, 0, 2097152 * sizeof(float), stream);
  hipMemsetAsync(zb, 0, 1536 * sizeof(float), stream);

  k_pack_w3<<<384, 256, 0, stream>>>(Whh_e, 512, 0, W3e);
  k_pack_w3<<<384, 256, 0, stream>>>(Whh_d, 512, 0, W3d);

  // GIe = emb_enc[src] @ Wih_e^T + bih_e   (single-pass bf16)
  k_mfma_gemm<<<dim3(1536 / 128, 4096 / 128), 256, 0, stream>>>(
      nullptr, emb_e, src, 1, Wih_e, 512, bih_e, GIe, 1536L, 32L * 1536L,
      4096, 1536, 512, 0, 1);
  // GId = emb_dec[tgt] @ Wih_d[:, :512]^T + bih_d   (single-pass bf16)
  k_mfma_gemm<<<dim3(1536 / 128, (2016 + 127) / 128), 256, 0, stream>>>(
      nullptr, emb_d, tgt, 2, Wih_d, 1024, bih_d, GId, 1536L, 32L * 1536L,
      2016, 1536, 512, 0, 1);

  k_enc_all<<<32, 1024, 0, stream>>>(GIe, W3e, bhh_e, lens, h0, EO16, EO32);

  // GV = EO32 @ Wih_d[:,512:1024]^T (f16 out, zero bias, 3-pass)
  k_mfma_gemm<<<dim3(1536 / 128, 4096 / 128), 256, 0, stream>>>(
      EO32, nullptr, nullptr, 0, Wih_d + 512, 1024, zb, GV, 1536L, 49152L,
      4096, 1536, 512, 2, 3);

  k_dec_all<<<32, 1024, 0, stream>>>(GId, EO16, W3d, GV, bhh_d, lens, h0,
                                     hctx, attns);

  // cc = tanh([hn|ctx] @ Wc^T + bc) (3-pass)
  k_mfma_gemm<<<dim3(512 / 128, (2016 + 127) / 128), 256, 0, stream>>>(
      hctx, nullptr, nullptr, 0, Wc, 1024, bc, ccall, 512L, 16384L,
      2016, 512, 1024, 1, 3);

  // logits = ccall @ Wo^T + bo (3-pass)
  k_mfma_gemm<<<dim3(V_ / 128, (2016 + 127) / 128), 256, 0, stream>>>(
      ccall, nullptr, nullptr, 0, Wo, 512, bo, logits,
      (long)STEPS_ * V_, (long)V_, 2016, 32000, 512, 0, 3);
}